// Round 1
// baseline (763.656 us; speedup 1.0000x reference)
//
#include <hip/hip_runtime.h>
#include <math.h>

#define NN 32768
#define DD 512
#define PP 256
#define LV 8
#define GR 64            // rows per gemm block
#define EMIT_BLOCKS 4096

typedef float f4 __attribute__((ext_vector_type(4)));

__device__ __forceinline__ unsigned long long umin64(unsigned long long a, unsigned long long b)
{
    return b < a ? b : a;   // lexicographic (value bits, col) min == first-index argmin
}

// ---------------------------------------------------------------- cnorm[j] = sum_d cb[j][d]^2  (blocks 0..3, tree identical to prior passing kernel)
//                                                                  cbT[d][j] = cb[j][d]        (blocks 4..67)
__global__ __launch_bounds__(256) void prep_kernel(const float* __restrict__ cb,
                                                   float* __restrict__ cnorm,
                                                   float* __restrict__ cbT)
{
    const int t = threadIdx.x;
    if (blockIdx.x < 4) {
        __shared__ float xp[256];
        const int r = t & 63, q = t >> 6;
        const float* row = cb + (size_t)(blockIdx.x * 64 + r) * DD + q * 128;
        float s = 0.f;
        #pragma unroll 8
        for (int f = 0; f < 32; f++) {
            f4 v = *(const f4*)&row[f * 4];
            s += v.x * v.x; s += v.y * v.y; s += v.z * v.z; s += v.w * v.w;
        }
        xp[q * 64 + r] = s;
        __syncthreads();
        if (t < 64) cnorm[blockIdx.x * 64 + t] = (xp[t] + xp[64 + t]) + (xp[128 + t] + xp[192 + t]);
    } else {
        const int d0 = (blockIdx.x - 4) * 8;
        f4 v0 = *(const f4*)&cb[(size_t)t * DD + d0];
        f4 v1 = *(const f4*)&cb[(size_t)t * DD + d0 + 4];
        cbT[(size_t)(d0 + 0) * PP + t] = v0.x;
        cbT[(size_t)(d0 + 1) * PP + t] = v0.y;
        cbT[(size_t)(d0 + 2) * PP + t] = v0.z;
        cbT[(size_t)(d0 + 3) * PP + t] = v0.w;
        cbT[(size_t)(d0 + 4) * PP + t] = v1.x;
        cbT[(size_t)(d0 + 5) * PP + t] = v1.y;
        cbT[(size_t)(d0 + 6) * PP + t] = v1.z;
        cbT[(size_t)(d0 + 7) * PP + t] = v1.w;
    }
}

// ---------------------------------------------------------------- T identity part: T[l][s] = (u<=cp) ? cb[s] : 0
__global__ __launch_bounds__(256) void buildT_A_kernel(const float* __restrict__ cb,
                                                       const float* __restrict__ nu,
                                                       const float* __restrict__ cp_p,
                                                       float* __restrict__ T)
{
    const int l = blockIdx.x, p = blockIdx.y;
    const int t = threadIdx.x;
    const float cp = cp_p[0];
    #pragma unroll 1
    for (int it = 0; it < 8; it++) {
        int s = p * 16 + it * 2 + (t >> 7);       // wave-uniform row
        float u = nu[l * PP + s];
        int d4 = (t & 127) * 4;
        f4 v = {0.f, 0.f, 0.f, 0.f};
        if (u <= cp) v = *(const f4*)&cb[(size_t)s * DD + d4];
        *(f4*)&T[((size_t)l * PP + s) * DD + d4] = v;
    }
}

// ---------------------------------------------------------------- T remap part: ~10% rows scatter-add
__global__ __launch_bounds__(256) void buildT_B_kernel(const float* __restrict__ cb,
                                                       const float* __restrict__ nu,
                                                       const float* __restrict__ cp_p,
                                                       float* __restrict__ T)
{
    const int l = blockIdx.x;
    const int t = threadIdx.x;
    const float cp = cp_p[0];
    __shared__ int lj[PP], ls[PP];
    __shared__ int cnt;
    if (t == 0) cnt = 0;
    __syncthreads();
    float u = nu[l * PP + t];
    if (u > cp) {
        float step = (1.0f - cp) / 256.0f;                 // mirrors (1.0-cp)/p_cb fp32
        int integer = (int)floorf((u - cp) / step);
        int src = (t + 1 + integer) & 255;
        int pos = atomicAdd(&cnt, 1);
        lj[pos] = t; ls[pos] = src;
    }
    __syncthreads();
    int n = cnt;
    for (int i = 0; i < n; i++) {
        int jj = lj[i], ss = ls[i];
        float*       dst = &T[((size_t)l * PP + ss) * DD];
        const float* sr  = &cb[(size_t)jj * DD];
        atomicAdd(&dst[t * 2],     sr[t * 2]);
        atomicAdd(&dst[t * 2 + 1], sr[t * 2 + 1]);
    }
}

// ---------------------------------------------------------------- scores + prefix argmin -> idx[N][8]
// Thread tile: 8 rows x 8 consecutive cols via transposed codebook.
//  - ds_read_b128 per 32 FMAs (was per 16) -> LDS pipe 768 cyc/CU < 1024 VALU cyc -> VALU-bound
//  - cbT loads coalesced (was 64x 2KB-strided requests/instr)
//  - argmin in registers via u64-packed shuffle butterfly (drops 66KB score LDS + serial scan)
// Score arithmetic is bit-identical to the prior passing kernel (same per-column FMA order,
// same (xn + cn) + (-2*acc) expression, same xn/cnorm reduction trees).
__global__ __launch_bounds__(256, 2) void gemm_argmin_kernel(const float* __restrict__ x,
                                                             const float* __restrict__ cbT,
                                                             const float* __restrict__ cnorm,
                                                             int* __restrict__ idx)
{
    __shared__ float sm[GR * 128];    // x tile [64][128]
    __shared__ float xp[256];
    __shared__ float xn_sm[GR];

    const int t       = threadIdx.x;
    const int row0    = blockIdx.x * GR;
    const int cl      = t & 31;                       // col group: cols cl*8 .. cl*8+7
    const int c0      = cl * 8;
    const int rowbase = (t >> 6) * 16 + ((t >> 5) & 1) * 8;   // half-wave-uniform
    const float* xrow = sm + rowbase * 128;

    f4 cn0 = *(const f4*)&cnorm[c0];
    f4 cn1 = *(const f4*)&cnorm[c0 + 4];

    f4 acc0[8], acc1[8];
    {
        f4 z = {0.f, 0.f, 0.f, 0.f};
        #pragma unroll
        for (int r = 0; r < 8; r++) { acc0[r] = z; acc1[r] = z; }
    }

    for (int dc = 0; dc < DD; dc += 128) {
        __syncthreads();
        #pragma unroll
        for (int k = 0; k < 8; k++) {           // stage x[64][128]: 2048 float4
            int i = t + k * 256;
            int r = i >> 5, f = i & 31;
            *(f4*)&sm[r * 128 + f * 4] = *(const f4*)&x[(size_t)(row0 + r) * DD + dc + f * 4];
        }
        __syncthreads();
        const float* bbase = cbT + (size_t)dc * PP + c0;
        #pragma unroll 1
        for (int dd = 0; dd < 128; dd += 4) {
            const float* bp = bbase + (size_t)dd * PP;
            f4 b00 = *(const f4*)&bp[0];            // dim dd+0, cols c0..c0+3
            f4 b01 = *(const f4*)&bp[4];            // dim dd+0, cols c0+4..c0+7
            f4 b10 = *(const f4*)&bp[PP];
            f4 b11 = *(const f4*)&bp[PP + 4];
            f4 b20 = *(const f4*)&bp[2 * PP];
            f4 b21 = *(const f4*)&bp[2 * PP + 4];
            f4 b30 = *(const f4*)&bp[3 * PP];
            f4 b31 = *(const f4*)&bp[3 * PP + 4];
            f4 xa[8];
            #pragma unroll
            for (int rr = 0; rr < 8; rr++) xa[rr] = *(const f4*)&xrow[rr * 128 + dd];
            #pragma unroll
            for (int rr = 0; rr < 8; rr++) {
                acc0[rr] += xa[rr].x * b00;         // k ascending per column: bit-identical
                acc0[rr] += xa[rr].y * b10;
                acc0[rr] += xa[rr].z * b20;
                acc0[rr] += xa[rr].w * b30;
                acc1[rr] += xa[rr].x * b01;
                acc1[rr] += xa[rr].y * b11;
                acc1[rr] += xa[rr].z * b21;
                acc1[rr] += xa[rr].w * b31;
            }
        }
    }
    __syncthreads();

    // xn[r]: tree identical to prior passing kernel (4-way 128-col split + pairwise)
    {
        const int r = t & 63, q = t >> 6;
        const float* xr = &x[(size_t)(row0 + r) * DD + q * 128];
        float s = 0.f;
        #pragma unroll 8
        for (int f = 0; f < 32; f++) {
            f4 v = *(const f4*)&xr[f * 4];
            s += v.x * v.x; s += v.y * v.y; s += v.z * v.z; s += v.w * v.w;
        }
        xp[q * 64 + r] = s;
    }
    __syncthreads();
    if (t < 64) xn_sm[t] = (xp[t] + xp[64 + t]) + (xp[128 + t] + xp[192 + t]);
    __syncthreads();

    // prefix argmin: u64 key = (float bits << 32) | col; all dists positive -> bits monotonic.
    #pragma unroll 1
    for (int rr = 0; rr < 8; rr++) {
        const float xn = xn_sm[rowbase + rr];
        float a0 = (xn + cn0.x) + (-2.f * acc0[rr].x);
        float a1 = (xn + cn0.y) + (-2.f * acc0[rr].y);
        float a2 = (xn + cn0.z) + (-2.f * acc0[rr].z);
        float a3 = (xn + cn0.w) + (-2.f * acc0[rr].w);
        float a4 = (xn + cn1.x) + (-2.f * acc1[rr].x);
        float a5 = (xn + cn1.y) + (-2.f * acc1[rr].y);
        float a6 = (xn + cn1.z) + (-2.f * acc1[rr].z);
        float a7 = (xn + cn1.w) + (-2.f * acc1[rr].w);
        unsigned long long k0 = ((unsigned long long)__float_as_uint(a0) << 32) | (unsigned)(c0 + 0);
        unsigned long long k1 = ((unsigned long long)__float_as_uint(a1) << 32) | (unsigned)(c0 + 1);
        unsigned long long k2 = ((unsigned long long)__float_as_uint(a2) << 32) | (unsigned)(c0 + 2);
        unsigned long long k3 = ((unsigned long long)__float_as_uint(a3) << 32) | (unsigned)(c0 + 3);
        unsigned long long k4 = ((unsigned long long)__float_as_uint(a4) << 32) | (unsigned)(c0 + 4);
        unsigned long long k5 = ((unsigned long long)__float_as_uint(a5) << 32) | (unsigned)(c0 + 5);
        unsigned long long k6 = ((unsigned long long)__float_as_uint(a6) << 32) | (unsigned)(c0 + 6);
        unsigned long long k7 = ((unsigned long long)__float_as_uint(a7) << 32) | (unsigned)(c0 + 7);
        unsigned long long s2 = umin64(k0, k1);                              // cols 0..1   (valid at cl==0)
        unsigned long long s4 = umin64(s2, umin64(k2, k3));                  // cols 0..3
        unsigned long long s8 = umin64(s4, umin64(umin64(k4, k5), umin64(k6, k7)));
        unsigned long long m = s8, o;
        o = __shfl_xor(m, 1);  m = umin64(m, o);  unsigned long long s16  = m;   // masks <=16 stay
        o = __shfl_xor(m, 2);  m = umin64(m, o);  unsigned long long s32  = m;   // inside the 32-half
        o = __shfl_xor(m, 4);  m = umin64(m, o);  unsigned long long s64  = m;
        o = __shfl_xor(m, 8);  m = umin64(m, o);  unsigned long long s128 = m;
        o = __shfl_xor(m, 16); m = umin64(m, o);  unsigned long long s256 = m;
        if (cl == 0) {
            int* od = &idx[(size_t)(row0 + rowbase + rr) * LV];
            od[0] = (int)(unsigned)s2;
            od[1] = (int)(unsigned)s4;
            od[2] = (int)(unsigned)s8;
            od[3] = (int)(unsigned)s16;
            od[4] = (int)(unsigned)s32;
            od[5] = (int)(unsigned)s64;
            od[6] = (int)(unsigned)s128;
            od[7] = (int)(unsigned)s256;
        }
    }
}

// ---------------------------------------------------------------- streaming emit: outs + sse partials
__global__ __launch_bounds__(256) void emit_kernel(const float* __restrict__ x,
                                                   const float* __restrict__ T,
                                                   const int* __restrict__ idx,
                                                   float* __restrict__ out,
                                                   float* __restrict__ partial)
{
    __shared__ int   idx_sm[64];
    __shared__ float red[4 * LV];
    const int t    = threadIdx.x;
    const int row0 = blockIdx.x * 8;
    if (t < 64) idx_sm[t] = idx[(size_t)row0 * LV + t];
    __syncthreads();

    float sse[LV];
    #pragma unroll
    for (int l = 0; l < LV; l++) sse[l] = 0.f;

    #pragma unroll 1
    for (int it = 0; it < 4; it++) {
        int rl = it * 2 + (t >> 7);               // wave-uniform local row
        int r  = row0 + rl;
        int d4 = (t & 127) * 4;
        f4 xv = __builtin_nontemporal_load((const f4*)&x[(size_t)r * DD + d4]);
        #pragma unroll
        for (int l = 0; l < LV; l++) {
            int id = idx_sm[rl * LV + l];
            f4 q = *(const f4*)&T[((size_t)l * PP + id) * DD + d4];
            float dx0 = q.x - xv.x, dx1 = q.y - xv.y, dx2 = q.z - xv.z, dx3 = q.w - xv.w;
            f4 o;
            o.x = xv.x + dx0; o.y = xv.y + dx1; o.z = xv.z + dx2; o.w = xv.w + dx3;  // x + (q - x)
            __builtin_nontemporal_store(o, (f4*)&out[((size_t)l * NN + r) * DD + d4]);
            sse[l] += dx0 * dx0; sse[l] += dx1 * dx1; sse[l] += dx2 * dx2; sse[l] += dx3 * dx3;
        }
    }
    #pragma unroll
    for (int l = 0; l < LV; l++) {
        float v = sse[l];
        #pragma unroll
        for (int off = 32; off; off >>= 1) v += __shfl_down(v, off);
        if ((t & 63) == 0) red[(t >> 6) * LV + l] = v;
    }
    __syncthreads();
    if (t < LV)
        partial[(size_t)t * EMIT_BLOCKS + blockIdx.x] =
            (red[t] + red[LV + t]) + (red[2 * LV + t] + red[3 * LV + t]);
}

// ---------------------------------------------------------------- actives copy + per-row prox SSE
__global__ __launch_bounds__(256) void actives_kernel(const float* __restrict__ cb,
                                                      const float* __restrict__ prev,
                                                      float* __restrict__ actv,
                                                      float* __restrict__ rowsse)
{
    const int t = threadIdx.x;
    size_t i = (size_t)blockIdx.x * 2048 + (size_t)t * 8;
    int row = (int)(i >> 9);                       // wave-uniform (64 thr x 8 floats = 512)
    f4 c0 = *(const f4*)&cb[i];
    f4 c1 = *(const f4*)&cb[i + 4];
    *(f4*)&actv[i]     = c0;
    *(f4*)&actv[i + 4] = c1;
    f4 p0 = *(const f4*)&prev[i];
    f4 p1 = *(const f4*)&prev[i + 4];
    float s = 0.f;
    s += (p0.x - c0.x) * (p0.x - c0.x); s += (p0.y - c0.y) * (p0.y - c0.y);
    s += (p0.z - c0.z) * (p0.z - c0.z); s += (p0.w - c0.w) * (p0.w - c0.w);
    s += (p1.x - c1.x) * (p1.x - c1.x); s += (p1.y - c1.y) * (p1.y - c1.y);
    s += (p1.z - c1.z) * (p1.z - c1.z); s += (p1.w - c1.w) * (p1.w - c1.w);
    #pragma unroll
    for (int off = 32; off; off >>= 1) s += __shfl_down(s, off);
    if ((t & 63) == 0) rowsse[row] = s;
}

// ---------------------------------------------------------------- losses
__global__ __launch_bounds__(256) void finalize_kernel(const float* __restrict__ partial,
                                                       const float* __restrict__ rowsse,
                                                       float* __restrict__ losses)
{
    __shared__ float ssev[LV];
    __shared__ float rs[PP];
    const int t = threadIdx.x;
    const int l = t >> 5, i = t & 31;
    float s = 0.f;
    for (int k = 0; k < EMIT_BLOCKS / 32; k++)
        s += partial[(size_t)l * EMIT_BLOCKS + i + k * 32];
    #pragma unroll
    for (int off = 16; off; off >>= 1) s += __shfl_down(s, off, 32);
    if (i == 0) ssev[l] = s;
    rs[t] = rowsse[t];
    __syncthreads();
    if (t == 0) {
        const float inv_nd = 1.0f / ((float)NN * (float)DD);
        float pacc = 0.f;
        int j = 0;
        for (int l2 = 0; l2 < LV; l2++) {
            float q = ssev[l2] * inv_nd;
            float e = (l2 <= 1) ? q : 0.f;                  // LAMBDA_C levels
            float prox = 0.f;
            if (l2 >= 1) {
                int np_ = 1 << l2;                          // 2^l rows
                while (j < np_) { pacc += rs[j]; j++; }
                prox = 0.33f * (pacc / ((float)np_ * (float)DD));
            }
            losses[l2] = q + 0.1f * e + prox;
        }
    }
}

// ----------------------------------------------------------------
extern "C" void kernel_launch(void* const* d_in, const int* in_sizes, int n_in,
                              void* d_out, int out_size, void* d_ws, size_t ws_size,
                              hipStream_t stream)
{
    const float* x    = (const float*)d_in[0];  // (32768,512)
    const float* cb   = (const float*)d_in[1];  // (256,512)
    const float* prev = (const float*)d_in[2];  // (256,512)
    const float* cp   = (const float*)d_in[3];  // (1,)
    const float* nu   = (const float*)d_in[4];  // (8,256)

    float* T       = (float*)d_ws;                      // 1,048,576 floats (4 MB)
    float* cnorm   = T + (size_t)LV * PP * DD;          // 256
    float* partial = cnorm + PP;                        // 8*4096 = 32768
    float* rowsse  = partial + LV * EMIT_BLOCKS;        // 256
    float* cbT     = rowsse + PP;                       // 512*256 = 131072 (cb transposed)
    int*   idx     = (int*)(cbT + (size_t)DD * PP);     // 32768*8 ints (1 MB)

    float* out    = (float*)d_out;                      // (8,32768,512)
    float* losses = out + (size_t)LV * NN * DD;         // (8,)
    float* actv   = losses + LV;                        // (256,512)

    prep_kernel<<<68, 256, 0, stream>>>(cb, cnorm, cbT);
    buildT_A_kernel<<<dim3(LV, 16), 256, 0, stream>>>(cb, nu, cp, T);
    buildT_B_kernel<<<LV, 256, 0, stream>>>(cb, nu, cp, T);
    gemm_argmin_kernel<<<NN / GR, 256, 0, stream>>>(x, cbT, cnorm, idx);
    emit_kernel<<<EMIT_BLOCKS, 256, 0, stream>>>(x, T, idx, out, partial);
    actives_kernel<<<64, 256, 0, stream>>>(cb, prev, actv, rowsse);
    finalize_kernel<<<1, 256, 0, stream>>>(partial, rowsse, losses);
}

// Round 2
// 687.325 us; speedup vs baseline: 1.1111x; 1.1111x over previous
//
#include <hip/hip_runtime.h>
#include <math.h>

#define NN 32768
#define DD 512
#define PP 256
#define LV 8
#define GR 64            // rows per gemm block
#define EMIT_BLOCKS 4096 // partial[] layout kept identical to the standalone-emit version

typedef float f4 __attribute__((ext_vector_type(4)));

__device__ __forceinline__ unsigned long long umin64(unsigned long long a, unsigned long long b)
{
    return b < a ? b : a;   // lexicographic (value bits, col) min == first-index argmin
}

// ---------------------------------------------------------------- cnorm[j] = sum_d cb[j][d]^2  (blocks 0..3)
//                                                                  cbT[d][j] = cb[j][d]        (blocks 4..67)
__global__ __launch_bounds__(256) void prep_kernel(const float* __restrict__ cb,
                                                   float* __restrict__ cnorm,
                                                   float* __restrict__ cbT)
{
    const int t = threadIdx.x;
    if (blockIdx.x < 4) {
        __shared__ float xp[256];
        const int r = t & 63, q = t >> 6;
        const float* row = cb + (size_t)(blockIdx.x * 64 + r) * DD + q * 128;
        float s = 0.f;
        #pragma unroll 8
        for (int f = 0; f < 32; f++) {
            f4 v = *(const f4*)&row[f * 4];
            s += v.x * v.x; s += v.y * v.y; s += v.z * v.z; s += v.w * v.w;
        }
        xp[q * 64 + r] = s;
        __syncthreads();
        if (t < 64) cnorm[blockIdx.x * 64 + t] = (xp[t] + xp[64 + t]) + (xp[128 + t] + xp[192 + t]);
    } else {
        const int d0 = (blockIdx.x - 4) * 8;
        f4 v0 = *(const f4*)&cb[(size_t)t * DD + d0];
        f4 v1 = *(const f4*)&cb[(size_t)t * DD + d0 + 4];
        cbT[(size_t)(d0 + 0) * PP + t] = v0.x;
        cbT[(size_t)(d0 + 1) * PP + t] = v0.y;
        cbT[(size_t)(d0 + 2) * PP + t] = v0.z;
        cbT[(size_t)(d0 + 3) * PP + t] = v0.w;
        cbT[(size_t)(d0 + 4) * PP + t] = v1.x;
        cbT[(size_t)(d0 + 5) * PP + t] = v1.y;
        cbT[(size_t)(d0 + 6) * PP + t] = v1.z;
        cbT[(size_t)(d0 + 7) * PP + t] = v1.w;
    }
}

// ---------------------------------------------------------------- T identity part: T[l][s] = (u<=cp) ? cb[s] : 0
__global__ __launch_bounds__(256) void buildT_A_kernel(const float* __restrict__ cb,
                                                       const float* __restrict__ nu,
                                                       const float* __restrict__ cp_p,
                                                       float* __restrict__ T)
{
    const int l = blockIdx.x, p = blockIdx.y;
    const int t = threadIdx.x;
    const float cp = cp_p[0];
    #pragma unroll 1
    for (int it = 0; it < 8; it++) {
        int s = p * 16 + it * 2 + (t >> 7);       // wave-uniform row
        float u = nu[l * PP + s];
        int d4 = (t & 127) * 4;
        f4 v = {0.f, 0.f, 0.f, 0.f};
        if (u <= cp) v = *(const f4*)&cb[(size_t)s * DD + d4];
        *(f4*)&T[((size_t)l * PP + s) * DD + d4] = v;
    }
}

// ---------------------------------------------------------------- T remap part: ~10% rows scatter-add
__global__ __launch_bounds__(256) void buildT_B_kernel(const float* __restrict__ cb,
                                                       const float* __restrict__ nu,
                                                       const float* __restrict__ cp_p,
                                                       float* __restrict__ T)
{
    const int l = blockIdx.x;
    const int t = threadIdx.x;
    const float cp = cp_p[0];
    __shared__ int lj[PP], ls[PP];
    __shared__ int cnt;
    if (t == 0) cnt = 0;
    __syncthreads();
    float u = nu[l * PP + t];
    if (u > cp) {
        float step = (1.0f - cp) / 256.0f;                 // mirrors (1.0-cp)/p_cb fp32
        int integer = (int)floorf((u - cp) / step);
        int src = (t + 1 + integer) & 255;
        int pos = atomicAdd(&cnt, 1);
        lj[pos] = t; ls[pos] = src;
    }
    __syncthreads();
    int n = cnt;
    for (int i = 0; i < n; i++) {
        int jj = lj[i], ss = ls[i];
        float*       dst = &T[((size_t)l * PP + ss) * DD];
        const float* sr  = &cb[(size_t)jj * DD];
        atomicAdd(&dst[t * 2],     sr[t * 2]);
        atomicAdd(&dst[t * 2 + 1], sr[t * 2 + 1]);
    }
}

// ---------------------------------------------------------------- FUSED: scores + prefix argmin + emit
// Phase 1 (verbatim from passing r1 kernel): 8x8 thread tile GEMM + u64 shuffle argmin,
//   but idx goes to LDS instead of HBM.
// Phase 2: replicates the standalone emit kernel exactly per 8-row group g (same per-thread
//   iteration pattern, same shuffle tree, same partial[LV][4096] slot = blockIdx*8+g), so all
//   FP reduction orders are bit-identical. x re-read is L2-hot (staged by this block in phase 1);
//   out-stores (HBM pipe) of one resident block overlap FMAs (VALU pipe) of the co-resident one.
__global__ __launch_bounds__(256, 2) void gemm_emit_kernel(const float* __restrict__ x,
                                                           const float* __restrict__ cbT,
                                                           const float* __restrict__ cnorm,
                                                           const float* __restrict__ T,
                                                           float* __restrict__ out,
                                                           float* __restrict__ partial)
{
    __shared__ float sm[GR * 128];    // x tile [64][128]
    __shared__ float xp[256];
    __shared__ float xn_sm[GR];
    __shared__ int   idx_lds[GR * LV];
    __shared__ float red[4 * LV];

    const int t       = threadIdx.x;
    const int row0    = blockIdx.x * GR;
    const int cl      = t & 31;                       // col group: cols cl*8 .. cl*8+7
    const int c0      = cl * 8;
    const int rowbase = (t >> 6) * 16 + ((t >> 5) & 1) * 8;   // half-wave-uniform
    const float* xrow = sm + rowbase * 128;

    f4 cn0 = *(const f4*)&cnorm[c0];
    f4 cn1 = *(const f4*)&cnorm[c0 + 4];

    f4 acc0[8], acc1[8];
    {
        f4 z = {0.f, 0.f, 0.f, 0.f};
        #pragma unroll
        for (int r = 0; r < 8; r++) { acc0[r] = z; acc1[r] = z; }
    }

    for (int dc = 0; dc < DD; dc += 128) {
        __syncthreads();
        #pragma unroll
        for (int k = 0; k < 8; k++) {           // stage x[64][128]: 2048 float4
            int i = t + k * 256;
            int r = i >> 5, f = i & 31;
            *(f4*)&sm[r * 128 + f * 4] = *(const f4*)&x[(size_t)(row0 + r) * DD + dc + f * 4];
        }
        __syncthreads();
        const float* bbase = cbT + (size_t)dc * PP + c0;
        #pragma unroll 1
        for (int dd = 0; dd < 128; dd += 4) {
            const float* bp = bbase + (size_t)dd * PP;
            f4 b00 = *(const f4*)&bp[0];            // dim dd+0, cols c0..c0+3
            f4 b01 = *(const f4*)&bp[4];            // dim dd+0, cols c0+4..c0+7
            f4 b10 = *(const f4*)&bp[PP];
            f4 b11 = *(const f4*)&bp[PP + 4];
            f4 b20 = *(const f4*)&bp[2 * PP];
            f4 b21 = *(const f4*)&bp[2 * PP + 4];
            f4 b30 = *(const f4*)&bp[3 * PP];
            f4 b31 = *(const f4*)&bp[3 * PP + 4];
            f4 xa[8];
            #pragma unroll
            for (int rr = 0; rr < 8; rr++) xa[rr] = *(const f4*)&xrow[rr * 128 + dd];
            #pragma unroll
            for (int rr = 0; rr < 8; rr++) {
                acc0[rr] += xa[rr].x * b00;         // k ascending per column: bit-identical
                acc0[rr] += xa[rr].y * b10;
                acc0[rr] += xa[rr].z * b20;
                acc0[rr] += xa[rr].w * b30;
                acc1[rr] += xa[rr].x * b01;
                acc1[rr] += xa[rr].y * b11;
                acc1[rr] += xa[rr].z * b21;
                acc1[rr] += xa[rr].w * b31;
            }
        }
    }
    __syncthreads();

    // xn[r]: tree identical to prior passing kernel (4-way 128-col split + pairwise)
    {
        const int r = t & 63, q = t >> 6;
        const float* xr = &x[(size_t)(row0 + r) * DD + q * 128];
        float s = 0.f;
        #pragma unroll 8
        for (int f = 0; f < 32; f++) {
            f4 v = *(const f4*)&xr[f * 4];
            s += v.x * v.x; s += v.y * v.y; s += v.z * v.z; s += v.w * v.w;
        }
        xp[q * 64 + r] = s;
    }
    __syncthreads();
    if (t < 64) xn_sm[t] = (xp[t] + xp[64 + t]) + (xp[128 + t] + xp[192 + t]);
    __syncthreads();

    // prefix argmin: u64 key = (float bits << 32) | col; all dists positive -> bits monotonic.
    #pragma unroll 1
    for (int rr = 0; rr < 8; rr++) {
        const float xn = xn_sm[rowbase + rr];
        float a0 = (xn + cn0.x) + (-2.f * acc0[rr].x);
        float a1 = (xn + cn0.y) + (-2.f * acc0[rr].y);
        float a2 = (xn + cn0.z) + (-2.f * acc0[rr].z);
        float a3 = (xn + cn0.w) + (-2.f * acc0[rr].w);
        float a4 = (xn + cn1.x) + (-2.f * acc1[rr].x);
        float a5 = (xn + cn1.y) + (-2.f * acc1[rr].y);
        float a6 = (xn + cn1.z) + (-2.f * acc1[rr].z);
        float a7 = (xn + cn1.w) + (-2.f * acc1[rr].w);
        unsigned long long k0 = ((unsigned long long)__float_as_uint(a0) << 32) | (unsigned)(c0 + 0);
        unsigned long long k1 = ((unsigned long long)__float_as_uint(a1) << 32) | (unsigned)(c0 + 1);
        unsigned long long k2 = ((unsigned long long)__float_as_uint(a2) << 32) | (unsigned)(c0 + 2);
        unsigned long long k3 = ((unsigned long long)__float_as_uint(a3) << 32) | (unsigned)(c0 + 3);
        unsigned long long k4 = ((unsigned long long)__float_as_uint(a4) << 32) | (unsigned)(c0 + 4);
        unsigned long long k5 = ((unsigned long long)__float_as_uint(a5) << 32) | (unsigned)(c0 + 5);
        unsigned long long k6 = ((unsigned long long)__float_as_uint(a6) << 32) | (unsigned)(c0 + 6);
        unsigned long long k7 = ((unsigned long long)__float_as_uint(a7) << 32) | (unsigned)(c0 + 7);
        unsigned long long s2 = umin64(k0, k1);                              // cols 0..1   (valid at cl==0)
        unsigned long long s4 = umin64(s2, umin64(k2, k3));                  // cols 0..3
        unsigned long long s8 = umin64(s4, umin64(umin64(k4, k5), umin64(k6, k7)));
        unsigned long long m = s8, o;
        o = __shfl_xor(m, 1);  m = umin64(m, o);  unsigned long long s16  = m;   // masks <=16 stay
        o = __shfl_xor(m, 2);  m = umin64(m, o);  unsigned long long s32  = m;   // inside the 32-half
        o = __shfl_xor(m, 4);  m = umin64(m, o);  unsigned long long s64  = m;
        o = __shfl_xor(m, 8);  m = umin64(m, o);  unsigned long long s128 = m;
        o = __shfl_xor(m, 16); m = umin64(m, o);  unsigned long long s256 = m;
        if (cl == 0) {
            int* od = &idx_lds[(rowbase + rr) * LV];
            od[0] = (int)(unsigned)s2;
            od[1] = (int)(unsigned)s4;
            od[2] = (int)(unsigned)s8;
            od[3] = (int)(unsigned)s16;
            od[4] = (int)(unsigned)s32;
            od[5] = (int)(unsigned)s64;
            od[6] = (int)(unsigned)s128;
            od[7] = (int)(unsigned)s256;
        }
    }
    __syncthreads();

    // ---- phase 2: emit, replicated per 8-row group g (bit-identical to standalone emit kernel)
    #pragma unroll 1
    for (int g = 0; g < 8; g++) {
        float sse[LV];
        #pragma unroll
        for (int l = 0; l < LV; l++) sse[l] = 0.f;

        #pragma unroll 1
        for (int it = 0; it < 4; it++) {
            int rl = g * 8 + it * 2 + (t >> 7);       // wave-uniform local row
            int r  = row0 + rl;
            int d4 = (t & 127) * 4;
            f4 xv = __builtin_nontemporal_load((const f4*)&x[(size_t)r * DD + d4]);
            #pragma unroll
            for (int l = 0; l < LV; l++) {
                int id = idx_lds[rl * LV + l];
                f4 q = *(const f4*)&T[((size_t)l * PP + id) * DD + d4];
                float dx0 = q.x - xv.x, dx1 = q.y - xv.y, dx2 = q.z - xv.z, dx3 = q.w - xv.w;
                f4 o;
                o.x = xv.x + dx0; o.y = xv.y + dx1; o.z = xv.z + dx2; o.w = xv.w + dx3;  // x + (q - x)
                __builtin_nontemporal_store(o, (f4*)&out[((size_t)l * NN + r) * DD + d4]);
                sse[l] += dx0 * dx0; sse[l] += dx1 * dx1; sse[l] += dx2 * dx2; sse[l] += dx3 * dx3;
            }
        }
        #pragma unroll
        for (int l = 0; l < LV; l++) {
            float v = sse[l];
            #pragma unroll
            for (int off = 32; off; off >>= 1) v += __shfl_down(v, off);
            if ((t & 63) == 0) red[(t >> 6) * LV + l] = v;
        }
        __syncthreads();
        if (t < LV)
            partial[(size_t)t * EMIT_BLOCKS + blockIdx.x * 8 + g] =
                (red[t] + red[LV + t]) + (red[2 * LV + t] + red[3 * LV + t]);
        __syncthreads();   // red[] reused next g
    }
}

// ---------------------------------------------------------------- actives copy + per-row prox SSE
__global__ __launch_bounds__(256) void actives_kernel(const float* __restrict__ cb,
                                                      const float* __restrict__ prev,
                                                      float* __restrict__ actv,
                                                      float* __restrict__ rowsse)
{
    const int t = threadIdx.x;
    size_t i = (size_t)blockIdx.x * 2048 + (size_t)t * 8;
    int row = (int)(i >> 9);                       // wave-uniform (64 thr x 8 floats = 512)
    f4 c0 = *(const f4*)&cb[i];
    f4 c1 = *(const f4*)&cb[i + 4];
    *(f4*)&actv[i]     = c0;
    *(f4*)&actv[i + 4] = c1;
    f4 p0 = *(const f4*)&prev[i];
    f4 p1 = *(const f4*)&prev[i + 4];
    float s = 0.f;
    s += (p0.x - c0.x) * (p0.x - c0.x); s += (p0.y - c0.y) * (p0.y - c0.y);
    s += (p0.z - c0.z) * (p0.z - c0.z); s += (p0.w - c0.w) * (p0.w - c0.w);
    s += (p1.x - c1.x) * (p1.x - c1.x); s += (p1.y - c1.y) * (p1.y - c1.y);
    s += (p1.z - c1.z) * (p1.z - c1.z); s += (p1.w - c1.w) * (p1.w - c1.w);
    #pragma unroll
    for (int off = 32; off; off >>= 1) s += __shfl_down(s, off);
    if ((t & 63) == 0) rowsse[row] = s;
}

// ---------------------------------------------------------------- losses
__global__ __launch_bounds__(256) void finalize_kernel(const float* __restrict__ partial,
                                                       const float* __restrict__ rowsse,
                                                       float* __restrict__ losses)
{
    __shared__ float ssev[LV];
    __shared__ float rs[PP];
    const int t = threadIdx.x;
    const int l = t >> 5, i = t & 31;
    float s = 0.f;
    for (int k = 0; k < EMIT_BLOCKS / 32; k++)
        s += partial[(size_t)l * EMIT_BLOCKS + i + k * 32];
    #pragma unroll
    for (int off = 16; off; off >>= 1) s += __shfl_down(s, off, 32);
    if (i == 0) ssev[l] = s;
    rs[t] = rowsse[t];
    __syncthreads();
    if (t == 0) {
        const float inv_nd = 1.0f / ((float)NN * (float)DD);
        float pacc = 0.f;
        int j = 0;
        for (int l2 = 0; l2 < LV; l2++) {
            float q = ssev[l2] * inv_nd;
            float e = (l2 <= 1) ? q : 0.f;                  // LAMBDA_C levels
            float prox = 0.f;
            if (l2 >= 1) {
                int np_ = 1 << l2;                          // 2^l rows
                while (j < np_) { pacc += rs[j]; j++; }
                prox = 0.33f * (pacc / ((float)np_ * (float)DD));
            }
            losses[l2] = q + 0.1f * e + prox;
        }
    }
}

// ----------------------------------------------------------------
extern "C" void kernel_launch(void* const* d_in, const int* in_sizes, int n_in,
                              void* d_out, int out_size, void* d_ws, size_t ws_size,
                              hipStream_t stream)
{
    const float* x    = (const float*)d_in[0];  // (32768,512)
    const float* cb   = (const float*)d_in[1];  // (256,512)
    const float* prev = (const float*)d_in[2];  // (256,512)
    const float* cp   = (const float*)d_in[3];  // (1,)
    const float* nu   = (const float*)d_in[4];  // (8,256)

    float* T       = (float*)d_ws;                      // 1,048,576 floats (4 MB)
    float* cnorm   = T + (size_t)LV * PP * DD;          // 256
    float* partial = cnorm + PP;                        // 8*4096 = 32768
    float* rowsse  = partial + LV * EMIT_BLOCKS;        // 256
    float* cbT     = rowsse + PP;                       // 512*256 = 131072 (cb transposed)

    float* out    = (float*)d_out;                      // (8,32768,512)
    float* losses = out + (size_t)LV * NN * DD;         // (8,)
    float* actv   = losses + LV;                        // (256,512)

    prep_kernel<<<68, 256, 0, stream>>>(cb, cnorm, cbT);
    buildT_A_kernel<<<dim3(LV, 16), 256, 0, stream>>>(cb, nu, cp, T);
    buildT_B_kernel<<<LV, 256, 0, stream>>>(cb, nu, cp, T);
    gemm_emit_kernel<<<NN / GR, 256, 0, stream>>>(x, cbT, cnorm, T, out, partial);
    actives_kernel<<<64, 256, 0, stream>>>(cb, prev, actv, rowsse);
    finalize_kernel<<<1, 256, 0, stream>>>(partial, rowsse, losses);
}

// Round 3
// 678.848 us; speedup vs baseline: 1.1249x; 1.0125x over previous
//
#include <hip/hip_runtime.h>
#include <math.h>

#define NN 32768
#define DD 512
#define PP 256
#define LV 8
#define GR 64            // rows per gemm block
#define EMIT_BLOCKS 4096 // partial[] layout kept identical to the standalone-emit version

typedef float f4 __attribute__((ext_vector_type(4)));

__device__ __forceinline__ unsigned long long umin64(unsigned long long a, unsigned long long b)
{
    return b < a ? b : a;   // lexicographic (value bits, col) min == first-index argmin
}

// ---------------------------------------------------------------- cnorm[j] = sum_d cb[j][d]^2  (blocks 0..3)
//                                                                  cbT[d][j] = cb[j][d]        (blocks 4..67)
__global__ __launch_bounds__(256) void prep_kernel(const float* __restrict__ cb,
                                                   float* __restrict__ cnorm,
                                                   float* __restrict__ cbT)
{
    const int t = threadIdx.x;
    if (blockIdx.x < 4) {
        __shared__ float xp[256];
        const int r = t & 63, q = t >> 6;
        const float* row = cb + (size_t)(blockIdx.x * 64 + r) * DD + q * 128;
        float s = 0.f;
        #pragma unroll 8
        for (int f = 0; f < 32; f++) {
            f4 v = *(const f4*)&row[f * 4];
            s += v.x * v.x; s += v.y * v.y; s += v.z * v.z; s += v.w * v.w;
        }
        xp[q * 64 + r] = s;
        __syncthreads();
        if (t < 64) cnorm[blockIdx.x * 64 + t] = (xp[t] + xp[64 + t]) + (xp[128 + t] + xp[192 + t]);
    } else {
        const int d0 = (blockIdx.x - 4) * 8;
        f4 v0 = *(const f4*)&cb[(size_t)t * DD + d0];
        f4 v1 = *(const f4*)&cb[(size_t)t * DD + d0 + 4];
        cbT[(size_t)(d0 + 0) * PP + t] = v0.x;
        cbT[(size_t)(d0 + 1) * PP + t] = v0.y;
        cbT[(size_t)(d0 + 2) * PP + t] = v0.z;
        cbT[(size_t)(d0 + 3) * PP + t] = v0.w;
        cbT[(size_t)(d0 + 4) * PP + t] = v1.x;
        cbT[(size_t)(d0 + 5) * PP + t] = v1.y;
        cbT[(size_t)(d0 + 6) * PP + t] = v1.z;
        cbT[(size_t)(d0 + 7) * PP + t] = v1.w;
    }
}

// ---------------------------------------------------------------- T identity part: T[l][s] = (u<=cp) ? cb[s] : 0
__global__ __launch_bounds__(256) void buildT_A_kernel(const float* __restrict__ cb,
                                                       const float* __restrict__ nu,
                                                       const float* __restrict__ cp_p,
                                                       float* __restrict__ T)
{
    const int l = blockIdx.x, p = blockIdx.y;
    const int t = threadIdx.x;
    const float cp = cp_p[0];
    #pragma unroll 1
    for (int it = 0; it < 8; it++) {
        int s = p * 16 + it * 2 + (t >> 7);       // wave-uniform row
        float u = nu[l * PP + s];
        int d4 = (t & 127) * 4;
        f4 v = {0.f, 0.f, 0.f, 0.f};
        if (u <= cp) v = *(const f4*)&cb[(size_t)s * DD + d4];
        *(f4*)&T[((size_t)l * PP + s) * DD + d4] = v;
    }
}

// ---------------------------------------------------------------- T remap part: ~10% rows scatter-add
__global__ __launch_bounds__(256) void buildT_B_kernel(const float* __restrict__ cb,
                                                       const float* __restrict__ nu,
                                                       const float* __restrict__ cp_p,
                                                       float* __restrict__ T)
{
    const int l = blockIdx.x;
    const int t = threadIdx.x;
    const float cp = cp_p[0];
    __shared__ int lj[PP], ls[PP];
    __shared__ int cnt;
    if (t == 0) cnt = 0;
    __syncthreads();
    float u = nu[l * PP + t];
    if (u > cp) {
        float step = (1.0f - cp) / 256.0f;                 // mirrors (1.0-cp)/p_cb fp32
        int integer = (int)floorf((u - cp) / step);
        int src = (t + 1 + integer) & 255;
        int pos = atomicAdd(&cnt, 1);
        lj[pos] = t; ls[pos] = src;
    }
    __syncthreads();
    int n = cnt;
    for (int i = 0; i < n; i++) {
        int jj = lj[i], ss = ls[i];
        float*       dst = &T[((size_t)l * PP + ss) * DD];
        const float* sr  = &cb[(size_t)jj * DD];
        atomicAdd(&dst[t * 2],     sr[t * 2]);
        atomicAdd(&dst[t * 2 + 1], sr[t * 2 + 1]);
    }
}

// ---------------------------------------------------------------- FUSED: scores + prefix argmin + emit
// r3 changes vs passing r2 kernel (both bit-exact):
//  - xn folded into the dc loop: thread (r,q) sums its 128-dim chunk from LDS during the dc
//    iteration where dc == q*128 (same values, same f4 add order, same xp tree). Removes the
//    64 MB global x re-read + one barrier phase.
//  - dd loop 2x-unrolled (step 8) with double-buffered b registers: next half-step's cbT loads
//    issue before the current FMA block; dd=0 set preloads before the staging barrier. FMA
//    accumulation order per column unchanged (dims ascending).
__global__ __launch_bounds__(256, 2) void gemm_emit_kernel(const float* __restrict__ x,
                                                           const float* __restrict__ cbT,
                                                           const float* __restrict__ cnorm,
                                                           const float* __restrict__ T,
                                                           float* __restrict__ out,
                                                           float* __restrict__ partial)
{
    __shared__ float sm[GR * 128];    // x tile [64][128]
    __shared__ float xp[256];
    __shared__ float xn_sm[GR];
    __shared__ int   idx_lds[GR * LV];
    __shared__ float red[4 * LV];

    const int t       = threadIdx.x;
    const int row0    = blockIdx.x * GR;
    const int cl      = t & 31;                       // col group: cols cl*8 .. cl*8+7
    const int c0      = cl * 8;
    const int rowbase = (t >> 6) * 16 + ((t >> 5) & 1) * 8;   // half-wave-uniform
    const float* xrow = sm + rowbase * 128;

    f4 cn0 = *(const f4*)&cnorm[c0];
    f4 cn1 = *(const f4*)&cnorm[c0 + 4];

    f4 acc0[8], acc1[8];
    {
        f4 z = {0.f, 0.f, 0.f, 0.f};
        #pragma unroll
        for (int r = 0; r < 8; r++) { acc0[r] = z; acc1[r] = z; }
    }

    float xns = 0.f;                 // folded ||x_r||^2 partial (chunk q = t>>6)

    for (int dc = 0; dc < DD; dc += 128) {
        __syncthreads();
        #pragma unroll
        for (int k = 0; k < 8; k++) {           // stage x[64][128]: 2048 float4
            int i = t + k * 256;
            int r = i >> 5, f = i & 31;
            *(f4*)&sm[r * 128 + f * 4] = *(const f4*)&x[(size_t)(row0 + r) * DD + dc + f * 4];
        }
        const float* bbase = cbT + (size_t)dc * PP + c0;
        // preload dd=0 b-regs while staging drains (global loads, no LDS dependency)
        f4 bA00 = *(const f4*)&bbase[0];
        f4 bA01 = *(const f4*)&bbase[4];
        f4 bA10 = *(const f4*)&bbase[PP];
        f4 bA11 = *(const f4*)&bbase[PP + 4];
        f4 bA20 = *(const f4*)&bbase[2 * PP];
        f4 bA21 = *(const f4*)&bbase[2 * PP + 4];
        f4 bA30 = *(const f4*)&bbase[3 * PP];
        f4 bA31 = *(const f4*)&bbase[3 * PP + 4];
        __syncthreads();
        #pragma unroll 1
        for (int dd = 0; dd < 128; dd += 8) {
            // prefetch dd+4 into bB
            const float* bpn = bbase + (size_t)(dd + 4) * PP;
            f4 bB00 = *(const f4*)&bpn[0];
            f4 bB01 = *(const f4*)&bpn[4];
            f4 bB10 = *(const f4*)&bpn[PP];
            f4 bB11 = *(const f4*)&bpn[PP + 4];
            f4 bB20 = *(const f4*)&bpn[2 * PP];
            f4 bB21 = *(const f4*)&bpn[2 * PP + 4];
            f4 bB30 = *(const f4*)&bpn[3 * PP];
            f4 bB31 = *(const f4*)&bpn[3 * PP + 4];
            {
                f4 xa[8];
                #pragma unroll
                for (int rr = 0; rr < 8; rr++) xa[rr] = *(const f4*)&xrow[rr * 128 + dd];
                #pragma unroll
                for (int rr = 0; rr < 8; rr++) {
                    acc0[rr] += xa[rr].x * bA00;         // k ascending per column: bit-identical
                    acc0[rr] += xa[rr].y * bA10;
                    acc0[rr] += xa[rr].z * bA20;
                    acc0[rr] += xa[rr].w * bA30;
                    acc1[rr] += xa[rr].x * bA01;
                    acc1[rr] += xa[rr].y * bA11;
                    acc1[rr] += xa[rr].z * bA21;
                    acc1[rr] += xa[rr].w * bA31;
                }
            }
            // prefetch dd+8 into bA (wave-uniform guard; wraps to chunk 0 on last iter, harmless)
            const int ddn = (dd + 8 < 128) ? dd + 8 : 0;
            const float* bpm = bbase + (size_t)ddn * PP;
            bA00 = *(const f4*)&bpm[0];
            bA01 = *(const f4*)&bpm[4];
            bA10 = *(const f4*)&bpm[PP];
            bA11 = *(const f4*)&bpm[PP + 4];
            bA20 = *(const f4*)&bpm[2 * PP];
            bA21 = *(const f4*)&bpm[2 * PP + 4];
            bA30 = *(const f4*)&bpm[3 * PP];
            bA31 = *(const f4*)&bpm[3 * PP + 4];
            {
                f4 xb[8];
                #pragma unroll
                for (int rr = 0; rr < 8; rr++) xb[rr] = *(const f4*)&xrow[rr * 128 + dd + 4];
                #pragma unroll
                for (int rr = 0; rr < 8; rr++) {
                    acc0[rr] += xb[rr].x * bB00;
                    acc0[rr] += xb[rr].y * bB10;
                    acc0[rr] += xb[rr].z * bB20;
                    acc0[rr] += xb[rr].w * bB30;
                    acc1[rr] += xb[rr].x * bB01;
                    acc1[rr] += xb[rr].y * bB11;
                    acc1[rr] += xb[rr].z * bB21;
                    acc1[rr] += xb[rr].w * bB31;
                }
            }
        }
        // folded xn: chunk q == this dc -> sum my row's 128 elems from LDS
        // (identical values + add order to the old global-x pass; sm stays valid until the
        //  next iteration's staging barrier)
        if ((t >> 6) == (dc >> 7)) {
            const float* xr2 = &sm[(t & 63) * 128];
            #pragma unroll 8
            for (int f = 0; f < 32; f++) {
                f4 v = *(const f4*)&xr2[f * 4];
                xns += v.x * v.x; xns += v.y * v.y; xns += v.z * v.z; xns += v.w * v.w;
            }
        }
    }

    // xn reduction tree: identical to prior passing kernel
    xp[(t >> 6) * 64 + (t & 63)] = xns;
    __syncthreads();
    if (t < 64) xn_sm[t] = (xp[t] + xp[64 + t]) + (xp[128 + t] + xp[192 + t]);
    __syncthreads();

    // prefix argmin: u64 key = (float bits << 32) | col; all dists positive -> bits monotonic.
    #pragma unroll 1
    for (int rr = 0; rr < 8; rr++) {
        const float xn = xn_sm[rowbase + rr];
        float a0 = (xn + cn0.x) + (-2.f * acc0[rr].x);
        float a1 = (xn + cn0.y) + (-2.f * acc0[rr].y);
        float a2 = (xn + cn0.z) + (-2.f * acc0[rr].z);
        float a3 = (xn + cn0.w) + (-2.f * acc0[rr].w);
        float a4 = (xn + cn1.x) + (-2.f * acc1[rr].x);
        float a5 = (xn + cn1.y) + (-2.f * acc1[rr].y);
        float a6 = (xn + cn1.z) + (-2.f * acc1[rr].z);
        float a7 = (xn + cn1.w) + (-2.f * acc1[rr].w);
        unsigned long long k0 = ((unsigned long long)__float_as_uint(a0) << 32) | (unsigned)(c0 + 0);
        unsigned long long k1 = ((unsigned long long)__float_as_uint(a1) << 32) | (unsigned)(c0 + 1);
        unsigned long long k2 = ((unsigned long long)__float_as_uint(a2) << 32) | (unsigned)(c0 + 2);
        unsigned long long k3 = ((unsigned long long)__float_as_uint(a3) << 32) | (unsigned)(c0 + 3);
        unsigned long long k4 = ((unsigned long long)__float_as_uint(a4) << 32) | (unsigned)(c0 + 4);
        unsigned long long k5 = ((unsigned long long)__float_as_uint(a5) << 32) | (unsigned)(c0 + 5);
        unsigned long long k6 = ((unsigned long long)__float_as_uint(a6) << 32) | (unsigned)(c0 + 6);
        unsigned long long k7 = ((unsigned long long)__float_as_uint(a7) << 32) | (unsigned)(c0 + 7);
        unsigned long long s2 = umin64(k0, k1);                              // cols 0..1   (valid at cl==0)
        unsigned long long s4 = umin64(s2, umin64(k2, k3));                  // cols 0..3
        unsigned long long s8 = umin64(s4, umin64(umin64(k4, k5), umin64(k6, k7)));
        unsigned long long m = s8, o;
        o = __shfl_xor(m, 1);  m = umin64(m, o);  unsigned long long s16  = m;   // masks <=16 stay
        o = __shfl_xor(m, 2);  m = umin64(m, o);  unsigned long long s32  = m;   // inside the 32-half
        o = __shfl_xor(m, 4);  m = umin64(m, o);  unsigned long long s64  = m;
        o = __shfl_xor(m, 8);  m = umin64(m, o);  unsigned long long s128 = m;
        o = __shfl_xor(m, 16); m = umin64(m, o);  unsigned long long s256 = m;
        if (cl == 0) {
            int* od = &idx_lds[(rowbase + rr) * LV];
            od[0] = (int)(unsigned)s2;
            od[1] = (int)(unsigned)s4;
            od[2] = (int)(unsigned)s8;
            od[3] = (int)(unsigned)s16;
            od[4] = (int)(unsigned)s32;
            od[5] = (int)(unsigned)s64;
            od[6] = (int)(unsigned)s128;
            od[7] = (int)(unsigned)s256;
        }
    }
    __syncthreads();

    // ---- phase 2: emit, replicated per 8-row group g (bit-identical to standalone emit kernel)
    #pragma unroll 1
    for (int g = 0; g < 8; g++) {
        float sse[LV];
        #pragma unroll
        for (int l = 0; l < LV; l++) sse[l] = 0.f;

        #pragma unroll 1
        for (int it = 0; it < 4; it++) {
            int rl = g * 8 + it * 2 + (t >> 7);       // wave-uniform local row
            int r  = row0 + rl;
            int d4 = (t & 127) * 4;
            f4 xv = __builtin_nontemporal_load((const f4*)&x[(size_t)r * DD + d4]);
            #pragma unroll
            for (int l = 0; l < LV; l++) {
                int id = idx_lds[rl * LV + l];
                f4 q = *(const f4*)&T[((size_t)l * PP + id) * DD + d4];
                float dx0 = q.x - xv.x, dx1 = q.y - xv.y, dx2 = q.z - xv.z, dx3 = q.w - xv.w;
                f4 o;
                o.x = xv.x + dx0; o.y = xv.y + dx1; o.z = xv.z + dx2; o.w = xv.w + dx3;  // x + (q - x)
                __builtin_nontemporal_store(o, (f4*)&out[((size_t)l * NN + r) * DD + d4]);
                sse[l] += dx0 * dx0; sse[l] += dx1 * dx1; sse[l] += dx2 * dx2; sse[l] += dx3 * dx3;
            }
        }
        #pragma unroll
        for (int l = 0; l < LV; l++) {
            float v = sse[l];
            #pragma unroll
            for (int off = 32; off; off >>= 1) v += __shfl_down(v, off);
            if ((t & 63) == 0) red[(t >> 6) * LV + l] = v;
        }
        __syncthreads();
        if (t < LV)
            partial[(size_t)t * EMIT_BLOCKS + blockIdx.x * 8 + g] =
                (red[t] + red[LV + t]) + (red[2 * LV + t] + red[3 * LV + t]);
        __syncthreads();   // red[] reused next g
    }
}

// ---------------------------------------------------------------- actives copy + per-row prox SSE
__global__ __launch_bounds__(256) void actives_kernel(const float* __restrict__ cb,
                                                      const float* __restrict__ prev,
                                                      float* __restrict__ actv,
                                                      float* __restrict__ rowsse)
{
    const int t = threadIdx.x;
    size_t i = (size_t)blockIdx.x * 2048 + (size_t)t * 8;
    int row = (int)(i >> 9);                       // wave-uniform (64 thr x 8 floats = 512)
    f4 c0 = *(const f4*)&cb[i];
    f4 c1 = *(const f4*)&cb[i + 4];
    *(f4*)&actv[i]     = c0;
    *(f4*)&actv[i + 4] = c1;
    f4 p0 = *(const f4*)&prev[i];
    f4 p1 = *(const f4*)&prev[i + 4];
    float s = 0.f;
    s += (p0.x - c0.x) * (p0.x - c0.x); s += (p0.y - c0.y) * (p0.y - c0.y);
    s += (p0.z - c0.z) * (p0.z - c0.z); s += (p0.w - c0.w) * (p0.w - c0.w);
    s += (p1.x - c1.x) * (p1.x - c1.x); s += (p1.y - c1.y) * (p1.y - c1.y);
    s += (p1.z - c1.z) * (p1.z - c1.z); s += (p1.w - c1.w) * (p1.w - c1.w);
    #pragma unroll
    for (int off = 32; off; off >>= 1) s += __shfl_down(s, off);
    if ((t & 63) == 0) rowsse[row] = s;
}

// ---------------------------------------------------------------- losses
__global__ __launch_bounds__(256) void finalize_kernel(const float* __restrict__ partial,
                                                       const float* __restrict__ rowsse,
                                                       float* __restrict__ losses)
{
    __shared__ float ssev[LV];
    __shared__ float rs[PP];
    const int t = threadIdx.x;
    const int l = t >> 5, i = t & 31;
    float s = 0.f;
    for (int k = 0; k < EMIT_BLOCKS / 32; k++)
        s += partial[(size_t)l * EMIT_BLOCKS + i + k * 32];
    #pragma unroll
    for (int off = 16; off; off >>= 1) s += __shfl_down(s, off, 32);
    if (i == 0) ssev[l] = s;
    rs[t] = rowsse[t];
    __syncthreads();
    if (t == 0) {
        const float inv_nd = 1.0f / ((float)NN * (float)DD);
        float pacc = 0.f;
        int j = 0;
        for (int l2 = 0; l2 < LV; l2++) {
            float q = ssev[l2] * inv_nd;
            float e = (l2 <= 1) ? q : 0.f;                  // LAMBDA_C levels
            float prox = 0.f;
            if (l2 >= 1) {
                int np_ = 1 << l2;                          // 2^l rows
                while (j < np_) { pacc += rs[j]; j++; }
                prox = 0.33f * (pacc / ((float)np_ * (float)DD));
            }
            losses[l2] = q + 0.1f * e + prox;
        }
    }
}

// ----------------------------------------------------------------
extern "C" void kernel_launch(void* const* d_in, const int* in_sizes, int n_in,
                              void* d_out, int out_size, void* d_ws, size_t ws_size,
                              hipStream_t stream)
{
    const float* x    = (const float*)d_in[0];  // (32768,512)
    const float* cb   = (const float*)d_in[1];  // (256,512)
    const float* prev = (const float*)d_in[2];  // (256,512)
    const float* cp   = (const float*)d_in[3];  // (1,)
    const float* nu   = (const float*)d_in[4];  // (8,256)

    float* T       = (float*)d_ws;                      // 1,048,576 floats (4 MB)
    float* cnorm   = T + (size_t)LV * PP * DD;          // 256
    float* partial = cnorm + PP;                        // 8*4096 = 32768
    float* rowsse  = partial + LV * EMIT_BLOCKS;        // 256
    float* cbT     = rowsse + PP;                       // 512*256 = 131072 (cb transposed)

    float* out    = (float*)d_out;                      // (8,32768,512)
    float* losses = out + (size_t)LV * NN * DD;         // (8,)
    float* actv   = losses + LV;                        // (256,512)

    prep_kernel<<<68, 256, 0, stream>>>(cb, cnorm, cbT);
    buildT_A_kernel<<<dim3(LV, 16), 256, 0, stream>>>(cb, nu, cp, T);
    buildT_B_kernel<<<LV, 256, 0, stream>>>(cb, nu, cp, T);
    gemm_emit_kernel<<<NN / GR, 256, 0, stream>>>(x, cbT, cnorm, T, out, partial);
    actives_kernel<<<64, 256, 0, stream>>>(cb, prev, actv, rowsse);
    finalize_kernel<<<1, 256, 0, stream>>>(partial, rowsse, losses);
}